// Round 12
// baseline (217.493 us; speedup 1.0000x reference)
//
#include <hip/hip_runtime.h>
#include <stdint.h>

#define D_DIM 512
#define NSTEPS 10
#define ALPHA0 0.1f
#define DT_C 0.1f
#define BETA_C 2.8982753492378875f

typedef __attribute__((ext_vector_type(8))) short short8;
typedef __attribute__((ext_vector_type(4))) float floatx4;
typedef __attribute__((ext_vector_type(4))) unsigned short ushortx4;
typedef unsigned int u32;

__device__ __forceinline__ unsigned short f32_to_bf16(float f) {
    union { float f; uint32_t u; } v;
    v.f = f;
    uint32_t u = v.u;
    return (unsigned short)((u + 0x7FFFu + ((u >> 16) & 1u)) >> 16);
}

__device__ __forceinline__ void async_load16(u32* lds, const u32* g) {
    __builtin_amdgcn_global_load_lds((const __attribute__((address_space(1))) u32*)g,
                                     (__attribute__((address_space(3))) u32*)lds, 16, 0, 0);
}

// ---------------------------------------------------------------------------
// Kernel 1: build L_rw in bf16 (row-major [e][d]). One wave per row.
// ---------------------------------------------------------------------------
__global__ __launch_bounds__(64) void prep_kernel(
    const float* __restrict__ W,
    unsigned short* __restrict__ Lbf)
{
    const int e = blockIdx.x;
    const int lane = threadIdx.x;
    const float* w = W + (size_t)e * D_DIM + lane * 8;
    const float4 v0 = *(const float4*)w;
    const float4 v1 = *(const float4*)(w + 4);
    float a[8] = { fabsf(v0.x), fabsf(v0.y), fabsf(v0.z), fabsf(v0.w),
                   fabsf(v1.x), fabsf(v1.y), fabsf(v1.z), fabsf(v1.w) };
    float s = a[0] + a[1] + a[2] + a[3] + a[4] + a[5] + a[6] + a[7];
#pragma unroll
    for (int off = 1; off < 64; off <<= 1) s += __shfl_xor(s, off, 64);
    const float inv = 1.0f / fmaxf(s, 1e-8f);
    short8 pk;
#pragma unroll
    for (int j = 0; j < 8; ++j) {
        const float diag = ((lane * 8 + j) == e) ? 1.0f : 0.0f;
        pk[j] = (short)f32_to_bf16(diag - a[j] * inv);
    }
    *(short8*)(Lbf + (size_t)e * D_DIM + lane * 8) = pk;
}

// ---------------------------------------------------------------------------
// Kernel 2: full 10-step settle + G build, ONE launch, 32 blocks x 1024 thr.
// Block owns 16 c-columns; wave w owns e-rows [32w, 32w+32) (2 m-frags).
// L streamed from L2 into LDS via global_load_lds (zero VGPR staging).
// ROUND-12 CHANGE -- fragment-order global source, linear LDS:
//   global_load_lds writes lds_base + lane*16 (HW-fixed, m104). The MFMA
//   A-frag lane l consumes is row (l&15), k-bytes (l>>4)*16. So the per-lane
//   GLOBAL source is chosen as exactly that fragment:
//     gsrc(l) = &L[ebase + (l&15)][kp*32 + (l>>4)*8]
//   Read back is then the trivial *(lt + lane*16) -- conflict-free linear
//   (round-11's row-major tile + XOR gave 1.02M conflict cycles).
//   - 4-slot ring, 2 KB/wave/slot (wave-private), depth-3 lead, vmcnt(6).
//   - 16%4==0 -> phase-clean across steps; prec hoisted (no in-loop drain).
// Abuf (A bf16 [c][d] swizzled, 16 KB) single-buffered; per-step barriers are
// raw lgkmcnt(0)+s_barrier (LDS-only) so the async ring survives them.
// Epilogue: Gbf = g*A10 + (1-g)I, diag folded (bf16).
// ---------------------------------------------------------------------------
__global__ __launch_bounds__(1024) void chain_kernel(
    const unsigned short* __restrict__ Lbf,   // [e][d]
    const float* __restrict__ prec,
    const float* __restrict__ gate_alpha,
    unsigned short* __restrict__ Gbf)         // [e][d], diag folded
{
    const int tid = threadIdx.x;
    const int wave = tid >> 6, lane = tid & 63;
    const int lrow = lane & 15, q = lane >> 4;
    const int c_glob = blockIdx.x * 16 + lrow;
    const int ebase = wave * 32;

    __shared__ unsigned short Abuf[16 * D_DIM];    // 16 KiB, swizzled [c][d]
    __shared__ unsigned short Lt[4][16][1024];     // 128 KiB: [slot][wave][2KB tile]
    char* abuf = (char*)Abuf;

    // fragment-order per-lane global source (see header comment):
    //   lane l covers row ebase+(l&15), k-chunk (l>>4); +kp*64 walks k-tiles
    const char* gsrc0 = (const char*)Lbf + ((size_t)(ebase + lrow) << 10) + ((size_t)q << 4);
    const char* gsrc1 = gsrc0 + (16u << 10);       // rows +16

    // prec hoisted: pr = precision[e] for this lane's 8 e's
    float pr[2][4];
#pragma unroll
    for (int m = 0; m < 2; ++m)
#pragma unroll
        for (int j = 0; j < 4; ++j)
            pr[m][j] = prec[ebase + m * 16 + q * 4 + j];

    floatx4 At[2], Bt[2];
#pragma unroll
    for (int m = 0; m < 2; ++m) {
#pragma unroll
        for (int j = 0; j < 4; ++j) {
            const int e = ebase + m * 16 + q * 4 + j;
            At[m][j] = (e == c_glob) ? 1.0f : 0.0f;
            Bt[m][j] = 0.0f;
        }
    }

    // init Abuf with A0 = I
#pragma unroll
    for (int m = 0; m < 2; ++m) {
        ushortx4 pk;
#pragma unroll
        for (int j = 0; j < 4; ++j) pk[j] = f32_to_bf16(At[m][j]);
        int byte = lrow * (D_DIM * 2) + (ebase + m * 16 + q * 4) * 2;
        byte ^= (lrow & 7) << 4;
        *(ushortx4*)(abuf + byte) = pk;
    }
    __syncthreads();

    // prime ring: tiles 0,1,2 into slots 0,1,2 (6 loads in flight)
#pragma unroll
    for (int t = 0; t < 3; ++t) {
        char* dst = (char*)&Lt[t][wave][0];
        async_load16((u32*)dst, (const u32*)(gsrc0 + t * 64));
        async_load16((u32*)(dst + 1024), (const u32*)(gsrc1 + t * 64));
    }

    for (int step = 0; step < NSTEPS; ++step) {
        floatx4 acc[2] = {};
#pragma unroll
        for (int kk = 0; kk < 16; ++kk) {
            // prefetch tile kk+3 into slot (kk+3)&3
            {
                const int kp = (kk + 3) & 15;
                char* dst = (char*)&Lt[(kk + 3) & 3][wave][0];
                async_load16((u32*)dst, (const u32*)(gsrc0 + kp * 64));
                async_load16((u32*)(dst + 1024), (const u32*)(gsrc1 + kp * 64));
            }
            // tile kk's 2 loads are the oldest of <=8 outstanding
            asm volatile("s_waitcnt vmcnt(6)" ::: "memory");
            __builtin_amdgcn_sched_barrier(0);

            const char* lt = (const char*)&Lt[kk & 3][wave][0];
            const short8 a0 = *(const short8*)(lt + lane * 16);
            const short8 a1 = *(const short8*)(lt + 1024 + lane * 16);

            int bbyte = lrow * (D_DIM * 2) + (kk * 32 + q * 8) * 2;
            bbyte ^= (lrow & 7) << 4;
            const short8 b = *(const short8*)(abuf + bbyte);

            acc[0] = __builtin_amdgcn_mfma_f32_16x16x32_bf16(a0, b, acc[0], 0, 0, 0);
            acc[1] = __builtin_amdgcn_mfma_f32_16x16x32_bf16(a1, b, acc[1], 0, 0, 0);
        }

#pragma unroll
        for (int m = 0; m < 2; ++m) {
#pragma unroll
            for (int j = 0; j < 4; ++j) {
                const int e = ebase + m * 16 + q * 4 + j;
                const float p = pr[m][j];
                const float tgt = (e == c_glob) ? p : 0.0f;
                const float force = -acc[m][j] - (ALPHA0 + p) * At[m][j]
                                    + tgt - BETA_C * Bt[m][j];
                Bt[m][j] += DT_C * force;
                At[m][j] += DT_C * Bt[m][j];
            }
        }

        if (step < NSTEPS - 1) {
            // all waves done reading Abuf (LDS ordering only; vmcnt untouched
            // so the async L ring stays in flight across the barrier)
            asm volatile("s_waitcnt lgkmcnt(0)\n\ts_barrier" ::: "memory");
            __builtin_amdgcn_sched_barrier(0);
#pragma unroll
            for (int m = 0; m < 2; ++m) {
                ushortx4 pk;
#pragma unroll
                for (int j = 0; j < 4; ++j) pk[j] = f32_to_bf16(At[m][j]);
                int byte = lrow * (D_DIM * 2) + (ebase + m * 16 + q * 4) * 2;
                byte ^= (lrow & 7) << 4;
                *(ushortx4*)(abuf + byte) = pk;
            }
            asm volatile("s_waitcnt lgkmcnt(0)\n\ts_barrier" ::: "memory");
            __builtin_amdgcn_sched_barrier(0);
        }
    }

    // epilogue: G = g*A10 + (1-g)I, diag folded into bf16
    const float g = tanhf(gate_alpha[0]);
#pragma unroll
    for (int m = 0; m < 2; ++m) {
#pragma unroll
        for (int j = 0; j < 4; ++j) {
            const int e = ebase + m * 16 + q * 4 + j;
            float val = g * At[m][j];
            if (e == c_glob) val += (1.0f - g);
            Gbf[(size_t)e * D_DIM + c_glob] = f32_to_bf16(val);
        }
    }
}

// ---------------------------------------------------------------------------
// Kernel 3: out = Hbf @ G^T (diag already folded into G).
// 512 blocks x 256 thr (4 waves), 32-row tiles. Per-wave independent async
// pipeline, ZERO barriers (unchanged -- passed rounds 9-11).
// ---------------------------------------------------------------------------
__global__ __launch_bounds__(256) void out_gemm(
    const float* __restrict__ H,              // [16384][512]
    const unsigned short* __restrict__ Gbf,   // [e][d] bf16, diag folded
    float* __restrict__ Out)
{
    const int r0 = blockIdx.x * 32;
    const int tid = threadIdx.x;
    const int wave = tid >> 6, lane = tid & 63;
    const int lrow = lane & 15, q = lane >> 4;

    __shared__ unsigned short Gl[2][64 * D_DIM];   // 2 x 64 KiB

    // stage chunk 0 (rows [wave*16, wave*16+16) of e-chunk 0)
#pragma unroll
    for (int i = 0; i < 16; ++i) {
        const int rl = wave * 16 + i;
        const char* gsrc = (const char*)Gbf + (size_t)rl * 1024
                           + ((lane * 16) ^ ((rl & 7) << 4));
        async_load16((u32*)((char*)Gl[0] + rl * 1024), (const u32*)gsrc);
    }

    // H tile -> registers (bf16)
    short8 Hreg[2][16];
#pragma unroll
    for (int m = 0; m < 2; ++m) {
#pragma unroll
        for (int kk = 0; kk < 16; ++kk) {
            const float* hs = H + (size_t)(r0 + m * 16 + lrow) * D_DIM + kk * 32 + q * 8;
            const float4 v0 = *(const float4*)hs;
            const float4 v1 = *(const float4*)(hs + 4);
            short8 pk;
            pk[0] = (short)f32_to_bf16(v0.x); pk[1] = (short)f32_to_bf16(v0.y);
            pk[2] = (short)f32_to_bf16(v0.z); pk[3] = (short)f32_to_bf16(v0.w);
            pk[4] = (short)f32_to_bf16(v1.x); pk[5] = (short)f32_to_bf16(v1.y);
            pk[6] = (short)f32_to_bf16(v1.z); pk[7] = (short)f32_to_bf16(v1.w);
            Hreg[m][kk] = pk;
        }
    }
    __builtin_amdgcn_sched_barrier(0);

    const int R = wave * 16 + lrow;          // chunk-local row this lane reads

    for (int c = 0; c < 8; ++c) {
        char* gl = (char*)Gl[c & 1];
        if (c + 1 < 8) {
            char* gld = (char*)Gl[(c + 1) & 1];
#pragma unroll
            for (int i = 0; i < 16; ++i) {
                const int rl = wave * 16 + i;
                const char* gsrc = (const char*)Gbf + (size_t)((c + 1) * 64 + rl) * 1024
                                   + ((lane * 16) ^ ((rl & 7) << 4));
                async_load16((u32*)(gld + rl * 1024), (const u32*)gsrc);
            }
            asm volatile("s_waitcnt vmcnt(16)" ::: "memory");
        } else {
            asm volatile("s_waitcnt vmcnt(0)" ::: "memory");
        }
        __builtin_amdgcn_sched_barrier(0);

        floatx4 acc[2] = {};
#pragma unroll
        for (int kk = 0; kk < 16; ++kk) {
            int byte = R * 1024 + (((kk * 32 + q * 8) * 2) ^ ((R & 7) << 4));
            const short8 b = *(const short8*)(gl + byte);
            acc[0] = __builtin_amdgcn_mfma_f32_16x16x32_bf16(Hreg[0][kk], b, acc[0], 0, 0, 0);
            acc[1] = __builtin_amdgcn_mfma_f32_16x16x32_bf16(Hreg[1][kk], b, acc[1], 0, 0, 0);
        }
#pragma unroll
        for (int m = 0; m < 2; ++m)
#pragma unroll
            for (int j = 0; j < 4; ++j)
                Out[(size_t)(r0 + m * 16 + q * 4 + j) * D_DIM + c * 64 + R] = acc[m][j];
    }
}

// ---------------------------------------------------------------------------
extern "C" void kernel_launch(void* const* d_in, const int* in_sizes, int n_in,
                              void* d_out, int out_size, void* d_ws, size_t ws_size,
                              hipStream_t stream)
{
    const float* H    = (const float*)d_in[0];   // (4,4096,512)
    const float* W    = (const float*)d_in[1];   // (512,512)
    const float* gate = (const float*)d_in[2];   // (1,)
    const float* prec = (const float*)d_in[3];   // (512,)
    float* out = (float*)d_out;
    char* ws = (char*)d_ws;

    unsigned short* Lbf = (unsigned short*)(ws);                 // 512 KiB
    unsigned short* Gbf = (unsigned short*)(ws + (512u << 10));  // 512 KiB

    prep_kernel<<<dim3(D_DIM), dim3(64), 0, stream>>>(W, Lbf);

    chain_kernel<<<dim3(D_DIM / 16), dim3(1024), 0, stream>>>(
        Lbf, prec, gate, Gbf);

    out_gemm<<<dim3(16384 / 32), dim3(256), 0, stream>>>(H, Gbf, out);
}

// Round 13
// 119.748 us; speedup vs baseline: 1.8163x; 1.8163x over previous
//
#include <hip/hip_runtime.h>
#include <stdint.h>

#define D_DIM 512
#define NSTEPS 10
#define ALPHA0 0.1f
#define DT_C 0.1f
#define BETA_C 2.8982753492378875f

typedef __attribute__((ext_vector_type(8))) short short8;
typedef __attribute__((ext_vector_type(4))) float floatx4;
typedef __attribute__((ext_vector_type(4))) unsigned short ushortx4;
typedef unsigned int u32;

__device__ __forceinline__ unsigned short f32_to_bf16(float f) {
    union { float f; uint32_t u; } v;
    v.f = f;
    uint32_t u = v.u;
    return (unsigned short)((u + 0x7FFFu + ((u >> 16) & 1u)) >> 16);
}

__device__ __forceinline__ void async_load16(u32* lds, const u32* g) {
    __builtin_amdgcn_global_load_lds((const __attribute__((address_space(1))) u32*)g,
                                     (__attribute__((address_space(3))) u32*)lds, 16, 0, 0);
}

// ---------------------------------------------------------------------------
// Kernel 1: build L_rw and store PRE-TILED in MFMA fragment order.
// Tile (eg, kk) = rows [eg*32, eg*32+32) x cols [kk*32, kk*32+32), stored as
// two 1KB halves (rows +0..16, +16..32); within a half, byte l*16 holds the
// fragment MFMA-lane l consumes: row (l&15), cols kk*32+(l>>4)*8 .. +8.
//   dst_byte((e,d)) = (eg*32 + kk*2 + half)*1024 + ((d8&3)*16 + (e&15))*16
//     where eg=e>>5, half=(e>>4)&1, kk=d8>>2, d8=d/8.
// Chain then DMA-loads each 1KB half fully CONTIGUOUS (perfect coalescing),
// LDS dest linear, LDS read linear lane*16 (zero conflicts) -- resolves the
// round-11 (conflicts) / round-12 (scattered global) tradeoff.
// ---------------------------------------------------------------------------
__global__ __launch_bounds__(64) void prep_kernel(
    const float* __restrict__ W,
    unsigned short* __restrict__ Ltl)    // 512 KiB, tiled layout
{
    const int e = blockIdx.x;
    const int lane = threadIdx.x;
    const float* w = W + (size_t)e * D_DIM + lane * 8;
    const float4 v0 = *(const float4*)w;
    const float4 v1 = *(const float4*)(w + 4);
    float a[8] = { fabsf(v0.x), fabsf(v0.y), fabsf(v0.z), fabsf(v0.w),
                   fabsf(v1.x), fabsf(v1.y), fabsf(v1.z), fabsf(v1.w) };
    float s = a[0] + a[1] + a[2] + a[3] + a[4] + a[5] + a[6] + a[7];
#pragma unroll
    for (int off = 1; off < 64; off <<= 1) s += __shfl_xor(s, off, 64);
    const float inv = 1.0f / fmaxf(s, 1e-8f);
    short8 pk;
#pragma unroll
    for (int j = 0; j < 8; ++j) {
        const float diag = ((lane * 8 + j) == e) ? 1.0f : 0.0f;
        pk[j] = (short)f32_to_bf16(diag - a[j] * inv);
    }
    const int eg = e >> 5, half = (e >> 4) & 1, r = e & 15;
    const int kk = lane >> 2, qp = lane & 3;
    char* dst = (char*)Ltl + ((size_t)(eg * 32 + kk * 2 + half) << 10)
                + ((size_t)(qp * 16 + r) << 4);
    *(short8*)dst = pk;
}

// ---------------------------------------------------------------------------
// Kernel 2: full 10-step settle + G build, ONE launch, 32 blocks x 1024 thr.
// Block owns 16 c-columns; wave w owns e-rows [32w, 32w+32) (2 m-frags).
// L streamed from L2 into LDS via global_load_lds from the TILED layout:
//   per kk, wave issues 2 x 1KB fully-contiguous loads (tile halves), 4-slot
//   ring (wave-private 2KB slots), depth-3 lead, s_waitcnt vmcnt(6).
//   LDS read = linear lane*16 (conflict-free).
// 16%4==0 -> ring phase-clean across steps; prec hoisted (no in-loop drain).
// Abuf (A bf16 [c][d] swizzled, 16 KB) single-buffered; per-step barriers are
// raw lgkmcnt(0)+s_barrier (LDS-only) so the async ring survives them.
// Epilogue: Gbf = g*A10 + (1-g)I, diag folded (bf16).
// ---------------------------------------------------------------------------
__global__ __launch_bounds__(1024) void chain_kernel(
    const unsigned short* __restrict__ Ltl,   // tiled L (see prep)
    const float* __restrict__ prec,
    const float* __restrict__ gate_alpha,
    unsigned short* __restrict__ Gbf)         // [e][d], diag folded
{
    const int tid = threadIdx.x;
    const int wave = tid >> 6, lane = tid & 63;
    const int lrow = lane & 15, q = lane >> 4;
    const int c_glob = blockIdx.x * 16 + lrow;
    const int ebase = wave * 32;

    __shared__ unsigned short Abuf[16 * D_DIM];    // 16 KiB, swizzled [c][d]
    __shared__ unsigned short Lt[4][16][1024];     // 128 KiB: [slot][wave][2KB tile]
    char* abuf = (char*)Abuf;

    // this wave's tile run: tiles (wave, kk) at base + kk*2048, halves +0/+1024
    const char* gbase = (const char*)Ltl + ((size_t)wave << 15) + ((size_t)lane << 4);

    // prec hoisted: pr = precision[e] for this lane's 8 e's
    float pr[2][4];
#pragma unroll
    for (int m = 0; m < 2; ++m)
#pragma unroll
        for (int j = 0; j < 4; ++j)
            pr[m][j] = prec[ebase + m * 16 + q * 4 + j];

    floatx4 At[2], Bt[2];
#pragma unroll
    for (int m = 0; m < 2; ++m) {
#pragma unroll
        for (int j = 0; j < 4; ++j) {
            const int e = ebase + m * 16 + q * 4 + j;
            At[m][j] = (e == c_glob) ? 1.0f : 0.0f;
            Bt[m][j] = 0.0f;
        }
    }

    // init Abuf with A0 = I
#pragma unroll
    for (int m = 0; m < 2; ++m) {
        ushortx4 pk;
#pragma unroll
        for (int j = 0; j < 4; ++j) pk[j] = f32_to_bf16(At[m][j]);
        int byte = lrow * (D_DIM * 2) + (ebase + m * 16 + q * 4) * 2;
        byte ^= (lrow & 7) << 4;
        *(ushortx4*)(abuf + byte) = pk;
    }
    __syncthreads();

    // prime ring: tiles 0,1,2 into slots 0,1,2 (6 loads in flight)
#pragma unroll
    for (int t = 0; t < 3; ++t) {
        char* dst = (char*)&Lt[t][wave][0];
        async_load16((u32*)dst, (const u32*)(gbase + t * 2048));
        async_load16((u32*)(dst + 1024), (const u32*)(gbase + t * 2048 + 1024));
    }

    for (int step = 0; step < NSTEPS; ++step) {
        floatx4 acc[2] = {};
#pragma unroll
        for (int kk = 0; kk < 16; ++kk) {
            // prefetch tile kk+3 into slot (kk+3)&3
            {
                const int kp = (kk + 3) & 15;
                char* dst = (char*)&Lt[(kk + 3) & 3][wave][0];
                async_load16((u32*)dst, (const u32*)(gbase + kp * 2048));
                async_load16((u32*)(dst + 1024), (const u32*)(gbase + kp * 2048 + 1024));
            }
            // tile kk's 2 loads are the oldest of <=8 outstanding
            asm volatile("s_waitcnt vmcnt(6)" ::: "memory");
            __builtin_amdgcn_sched_barrier(0);

            const char* lt = (const char*)&Lt[kk & 3][wave][0];
            const short8 a0 = *(const short8*)(lt + lane * 16);
            const short8 a1 = *(const short8*)(lt + 1024 + lane * 16);

            int bbyte = lrow * (D_DIM * 2) + (kk * 32 + q * 8) * 2;
            bbyte ^= (lrow & 7) << 4;
            const short8 b = *(const short8*)(abuf + bbyte);

            acc[0] = __builtin_amdgcn_mfma_f32_16x16x32_bf16(a0, b, acc[0], 0, 0, 0);
            acc[1] = __builtin_amdgcn_mfma_f32_16x16x32_bf16(a1, b, acc[1], 0, 0, 0);
        }

#pragma unroll
        for (int m = 0; m < 2; ++m) {
#pragma unroll
            for (int j = 0; j < 4; ++j) {
                const int e = ebase + m * 16 + q * 4 + j;
                const float p = pr[m][j];
                const float tgt = (e == c_glob) ? p : 0.0f;
                const float force = -acc[m][j] - (ALPHA0 + p) * At[m][j]
                                    + tgt - BETA_C * Bt[m][j];
                Bt[m][j] += DT_C * force;
                At[m][j] += DT_C * Bt[m][j];
            }
        }

        if (step < NSTEPS - 1) {
            // all waves done reading Abuf (LDS ordering only; vmcnt untouched
            // so the async L ring stays in flight across the barrier)
            asm volatile("s_waitcnt lgkmcnt(0)\n\ts_barrier" ::: "memory");
            __builtin_amdgcn_sched_barrier(0);
#pragma unroll
            for (int m = 0; m < 2; ++m) {
                ushortx4 pk;
#pragma unroll
                for (int j = 0; j < 4; ++j) pk[j] = f32_to_bf16(At[m][j]);
                int byte = lrow * (D_DIM * 2) + (ebase + m * 16 + q * 4) * 2;
                byte ^= (lrow & 7) << 4;
                *(ushortx4*)(abuf + byte) = pk;
            }
            asm volatile("s_waitcnt lgkmcnt(0)\n\ts_barrier" ::: "memory");
            __builtin_amdgcn_sched_barrier(0);
        }
    }

    // epilogue: G = g*A10 + (1-g)I, diag folded into bf16
    const float g = tanhf(gate_alpha[0]);
#pragma unroll
    for (int m = 0; m < 2; ++m) {
#pragma unroll
        for (int j = 0; j < 4; ++j) {
            const int e = ebase + m * 16 + q * 4 + j;
            float val = g * At[m][j];
            if (e == c_glob) val += (1.0f - g);
            Gbf[(size_t)e * D_DIM + c_glob] = f32_to_bf16(val);
        }
    }
}

// ---------------------------------------------------------------------------
// Kernel 3: out = Hbf @ G^T (diag already folded into G).
// 512 blocks x 256 thr (4 waves), 32-row tiles. Per-wave independent async
// pipeline, ZERO barriers (unchanged -- passed rounds 9-12).
// ---------------------------------------------------------------------------
__global__ __launch_bounds__(256) void out_gemm(
    const float* __restrict__ H,              // [16384][512]
    const unsigned short* __restrict__ Gbf,   // [e][d] bf16, diag folded
    float* __restrict__ Out)
{
    const int r0 = blockIdx.x * 32;
    const int tid = threadIdx.x;
    const int wave = tid >> 6, lane = tid & 63;
    const int lrow = lane & 15, q = lane >> 4;

    __shared__ unsigned short Gl[2][64 * D_DIM];   // 2 x 64 KiB

    // stage chunk 0 (rows [wave*16, wave*16+16) of e-chunk 0)
#pragma unroll
    for (int i = 0; i < 16; ++i) {
        const int rl = wave * 16 + i;
        const char* gsrc = (const char*)Gbf + (size_t)rl * 1024
                           + ((lane * 16) ^ ((rl & 7) << 4));
        async_load16((u32*)((char*)Gl[0] + rl * 1024), (const u32*)gsrc);
    }

    // H tile -> registers (bf16)
    short8 Hreg[2][16];
#pragma unroll
    for (int m = 0; m < 2; ++m) {
#pragma unroll
        for (int kk = 0; kk < 16; ++kk) {
            const float* hs = H + (size_t)(r0 + m * 16 + lrow) * D_DIM + kk * 32 + q * 8;
            const float4 v0 = *(const float4*)hs;
            const float4 v1 = *(const float4*)(hs + 4);
            short8 pk;
            pk[0] = (short)f32_to_bf16(v0.x); pk[1] = (short)f32_to_bf16(v0.y);
            pk[2] = (short)f32_to_bf16(v0.z); pk[3] = (short)f32_to_bf16(v0.w);
            pk[4] = (short)f32_to_bf16(v1.x); pk[5] = (short)f32_to_bf16(v1.y);
            pk[6] = (short)f32_to_bf16(v1.z); pk[7] = (short)f32_to_bf16(v1.w);
            Hreg[m][kk] = pk;
        }
    }
    __builtin_amdgcn_sched_barrier(0);

    const int R = wave * 16 + lrow;          // chunk-local row this lane reads

    for (int c = 0; c < 8; ++c) {
        char* gl = (char*)Gl[c & 1];
        if (c + 1 < 8) {
            char* gld = (char*)Gl[(c + 1) & 1];
#pragma unroll
            for (int i = 0; i < 16; ++i) {
                const int rl = wave * 16 + i;
                const char* gsrc = (const char*)Gbf + (size_t)((c + 1) * 64 + rl) * 1024
                                   + ((lane * 16) ^ ((rl & 7) << 4));
                async_load16((u32*)(gld + rl * 1024), (const u32*)gsrc);
            }
            asm volatile("s_waitcnt vmcnt(16)" ::: "memory");
        } else {
            asm volatile("s_waitcnt vmcnt(0)" ::: "memory");
        }
        __builtin_amdgcn_sched_barrier(0);

        floatx4 acc[2] = {};
#pragma unroll
        for (int kk = 0; kk < 16; ++kk) {
            int byte = R * 1024 + (((kk * 32 + q * 8) * 2) ^ ((R & 7) << 4));
            const short8 b = *(const short8*)(gl + byte);
            acc[0] = __builtin_amdgcn_mfma_f32_16x16x32_bf16(Hreg[0][kk], b, acc[0], 0, 0, 0);
            acc[1] = __builtin_amdgcn_mfma_f32_16x16x32_bf16(Hreg[1][kk], b, acc[1], 0, 0, 0);
        }
#pragma unroll
        for (int m = 0; m < 2; ++m)
#pragma unroll
            for (int j = 0; j < 4; ++j)
                Out[(size_t)(r0 + m * 16 + q * 4 + j) * D_DIM + c * 64 + R] = acc[m][j];
    }
}

// ---------------------------------------------------------------------------
extern "C" void kernel_launch(void* const* d_in, const int* in_sizes, int n_in,
                              void* d_out, int out_size, void* d_ws, size_t ws_size,
                              hipStream_t stream)
{
    const float* H    = (const float*)d_in[0];   // (4,4096,512)
    const float* W    = (const float*)d_in[1];   // (512,512)
    const float* gate = (const float*)d_in[2];   // (1,)
    const float* prec = (const float*)d_in[3];   // (512,)
    float* out = (float*)d_out;
    char* ws = (char*)d_ws;

    unsigned short* Ltl = (unsigned short*)(ws);                 // 512 KiB (tiled)
    unsigned short* Gbf = (unsigned short*)(ws + (512u << 10));  // 512 KiB

    prep_kernel<<<dim3(D_DIM), dim3(64), 0, stream>>>(W, Ltl);

    chain_kernel<<<dim3(D_DIM / 16), dim3(1024), 0, stream>>>(
        Ltl, prec, gate, Gbf);

    out_gemm<<<dim3(16384 / 32), dim3(256), 0, stream>>>(H, Gbf, out);
}